// Round 14
// baseline (126.377 us; speedup 1.0000x reference)
//
#include <hip/hip_runtime.h>

// s_gcn, plain-bf16 MFMA, two fused GEMM stages (R12 structure).
// R14: occupancy play. R12 kernel is 60 VGPR / 32 KB LDS -> 8 waves/SIMD and
//     5 blocks/CU are both legal; the limiter was DISPATCHED blocks (1024 =
//     4/CU -> avg residency ~1.6, occupancy 40%). Halve the t-window:
//     TWIN 32->16, grid 1024->2048 (8/CU dispatched, 4 resident, wave-capped).
//     Independent blocks interleave phases and hide each other's barrier
//     stalls -- the within-block pipeline (R13) couldn't (+3% only).
//     Keep VGPR <= 64 (do NOT carry R13's xq[8] b128 staging: 68 VGPR lands
//     in the 128-bucket -> 4 waves/SIMD).

typedef short short8 __attribute__((ext_vector_type(8)));
typedef float floatx4 __attribute__((ext_vector_type(4)));

#define K_NUM 3
#define C_IN  64
#define C_OUT 64
#define T_DIM 2048
#define V_DIM 25
#define N_DIM 16

#define TT    2
#define NSUB  8
#define TWIN  16
#define NWIN  (T_DIM / TWIN)   // 128 windows

#define WBUF_ELEMS (12*2*64*8)              // [nt12][ks2][lane64][j8] u16
#define ABUF_OFF   (WBUF_ELEMS*2)
#define ABUF_ELEMS (3*2*64*8)               // [k3][nt2][lane64][j8] u16
#define B2_OFF     (ABUF_OFF + ABUF_ELEMS*2)
#define B2_ELEMS   (4*2*64*4)               // [mt2_4][nt2][lane64][r4] f32

__device__ __forceinline__ unsigned short bf16_rne(float f) {
    unsigned int u = __builtin_bit_cast(unsigned int, f);
    unsigned int r = (u + 0x7FFFu + ((u >> 16) & 1u)) >> 16;
    return (unsigned short)r;
}

__global__ void sgcn_prep(const float* __restrict__ W, const float* __restrict__ A,
                          const float* __restrict__ b,
                          unsigned short* __restrict__ wbuf,
                          unsigned short* __restrict__ abuf,
                          float* __restrict__ b2buf) {
    int idx = blockIdx.x * 256 + threadIdx.x;
    if (idx < WBUF_ELEMS) {   // B-operand: n=o (lane&15), k=ci ((lane>>4)*8+j)
        int j = idx & 7, lane = (idx >> 3) & 63, ks = (idx >> 9) & 1, nt = idx >> 10;
        int o  = nt * 16 + (lane & 15);
        int ci = ks * 32 + ((lane >> 4) & 3) * 8 + j;
        wbuf[idx] = bf16_rne(W[o * C_IN + ci]);
    }
    if (idx < ABUF_ELEMS) {   // B-operand: n=w, k=v (K=32)
        int j = idx & 7, lane = (idx >> 3) & 63, nt = (idx >> 9) & 1, k = idx >> 10;
        int w = nt * 16 + (lane & 15);
        int v = ((lane >> 4) & 3) * 8 + j;
        abuf[idx] = (v < V_DIM && w < V_DIM) ? bf16_rne(A[(k * V_DIM + v) * V_DIM + w])
                                             : (unsigned short)0;
    }
    if (idx < B2_ELEMS) {     // bias folded through stage-2: sum_k b_kc * sum_v A[k][v][w]
        int r = idx & 3, lane = (idx >> 2) & 63, nt = (idx >> 8) & 1, mt2 = idx >> 9;
        int c = mt2 * 16 + ((lane >> 4) & 3) * 4 + r;
        int w = nt * 16 + (lane & 15);
        float val = 0.f;
        if (w < V_DIM) {
            for (int k = 0; k < K_NUM; ++k) {
                float cs = 0.f;
                for (int v = 0; v < V_DIM; ++v) cs += A[(k * V_DIM + v) * V_DIM + w];
                val += b[k * C_OUT + c] * cs;
            }
        }
        b2buf[idx] = val;
    }
}

__global__ __launch_bounds__(512)
void sgcn_main(const float* __restrict__ x,
               const unsigned short* __restrict__ wbuf,
               const unsigned short* __restrict__ abuf,
               const float* __restrict__ b2buf,
               float* __restrict__ out) {
    __shared__ __align__(16) unsigned short Xt[64 * 64];              // [col][ci^swz]  8 KB
    __shared__ __align__(16) unsigned short H2[K_NUM * TT * 64 * 32]; // [k][t][c][v^swz] 24 KB

    const int tid  = threadIdx.x;
    const int lane = tid & 63;
    const int wid  = tid >> 6;
    const int nb   = blockIdx.x >> 7;          // 16 n
    const int t_base = (blockIdx.x & 127) * TWIN;

    const int wm2 = wid & 1;   // stage-1: col half (= t), 2 m-tiles
    const int wq  = wid >> 1;  // stage-1: o quarter (3 n-tiles)
    const int mt2 = wid & 3, th = wid >> 2;   // stage-2: 4 c-tiles x 2 t

    // ---- hoisted loop-invariant fragments ----
    short8 wfr[3][2];
    #pragma unroll
    for (int ni = 0; ni < 3; ++ni)
        #pragma unroll
        for (int ks = 0; ks < 2; ++ks)
            wfr[ni][ks] = ((const short8*)wbuf)[(((wq * 3 + ni) * 2 + ks) * 64) + lane];
    short8 afr2[3][2];
    #pragma unroll
    for (int k = 0; k < 3; ++k)
        #pragma unroll
        for (int nt = 0; nt < 2; ++nt)
            afr2[k][nt] = ((const short8*)abuf)[((k * 2 + nt) * 64) + lane];
    floatx4 b2f[2];
    b2f[0] = reinterpret_cast<const floatx4*>(b2buf)[(mt2 * 2 + 0) * 64 + lane];
    b2f[1] = reinterpret_cast<const floatx4*>(b2buf)[(mt2 * 2 + 1) * 64 + lane];

    // zero never-written Xt pad cols (25..31, 57..63)
    for (int i = tid; i < 14 * 32; i += 512) {
        int pc = i >> 5, ciw = i & 31;
        int col = (pc < 7) ? (25 + pc) : (50 + pc);
        ((unsigned int*)Xt)[col * 32 + ciw] = 0u;
    }

    // ---- x prefetch: element u -> rows (2*ci2, 2*ci2+1), col cg ----
    float xa[4], xb[4];
    const float* xptr = x + ((size_t)nb * C_IN * T_DIM + t_base) * V_DIM;

    auto LOADX = [&](int ts) {
        const float* s = xptr + ts * TT * V_DIM;
        #pragma unroll
        for (int p = 0; p < 4; ++p) {
            int u = tid + p * 512;
            if (u < 1600) {
                int ci2 = u / 50, cg = u % 50;
                size_t off = (size_t)(2 * ci2) * (T_DIM * V_DIM) + cg;
                xa[p] = s[off];
                xb[p] = s[off + T_DIM * V_DIM];
            }
        }
    };
    auto WRITEX = [&]() {
        #pragma unroll
        for (int p = 0; p < 4; ++p) {
            int u = tid + p * 512;
            if (u < 1600) {
                int ci2 = u / 50, cg = u % 50;
                int t = cg / 25, v = cg - t * 25;
                int col = t * 32 + v;
                unsigned int pk = (unsigned int)bf16_rne(xa[p]) |
                                  ((unsigned int)bf16_rne(xb[p]) << 16);
                int sw = ci2 ^ (((col >> 1) & 7) << 2);
                ((unsigned int*)Xt)[col * 32 + sw] = pk;
            }
        }
    };

    LOADX(0);

    #pragma unroll 1
    for (int ts = 0; ts < NSUB; ++ts) {
        WRITEX();            // Xt(ts); safe: stage-1(ts-1) reads ended before barrier B(ts-1)
        __syncthreads();     // barrier A: Xt ready, stage-2(ts-1) H2 reads done

        // ---- stage-1: H^T = Xt * W  (M=64 col, N=192 o, K=64) ----
        short8 xfr[2][2];
        #pragma unroll
        for (int mi = 0; mi < 2; ++mi) {
            int acol = (wm2 * 2 + mi) * 16 + (lane & 15);
            #pragma unroll
            for (int ks = 0; ks < 2; ++ks) {
                int blk = (ks * 4 + ((lane >> 4) & 3)) ^ ((acol >> 1) & 7);
                xfr[mi][ks] = *(const short8*)&((unsigned int*)Xt)[acol * 32 + blk * 4];
            }
        }

        if (ts + 1 < NSUB) LOADX(ts + 1);   // hide HBM under MFMA

        floatx4 acc1[2][3];
        #pragma unroll
        for (int mi = 0; mi < 2; ++mi)
            #pragma unroll
            for (int ni = 0; ni < 3; ++ni)
                acc1[mi][ni] = floatx4{0.f, 0.f, 0.f, 0.f};

        #pragma unroll
        for (int mi = 0; mi < 2; ++mi)
            #pragma unroll
            for (int ni = 0; ni < 3; ++ni)
                #pragma unroll
                for (int ks = 0; ks < 2; ++ks)
                    acc1[mi][ni] = __builtin_amdgcn_mfma_f32_16x16x32_bf16(
                        xfr[mi][ks], wfr[ni][ks], acc1[mi][ni], 0, 0, 0);

        // ---- H2 write: thread holds 4 consecutive v for fixed (t=wm2, o) -> b64 ----
        #pragma unroll
        for (int mi = 0; mi < 2; ++mi) {
            int vb = mi * 16 + ((lane >> 4) & 3) * 4;
            #pragma unroll
            for (int ni = 0; ni < 3; ++ni) {
                int o = wq * 48 + ni * 16 + (lane & 15);
                int k = o >> 6, c = o & 63;
                int swv = vb ^ (((c >> 2) & 3) << 3);
                unsigned long long lo =
                    (unsigned long long)((unsigned int)bf16_rne(acc1[mi][ni][0]) |
                                         ((unsigned int)bf16_rne(acc1[mi][ni][1]) << 16));
                unsigned long long hi =
                    (unsigned long long)((unsigned int)bf16_rne(acc1[mi][ni][2]) |
                                         ((unsigned int)bf16_rne(acc1[mi][ni][3]) << 16));
                int idx16 = ((k * TT + wm2) * 64 + c) * 32 + swv;   // aligned 4
                ((unsigned long long*)H2)[idx16 >> 2] = lo | (hi << 32);
            }
        }
        __syncthreads();     // barrier B: H2 ready

        // ---- stage-2: OUT[c][w] = sum_k H_k * A_k  (M=64, N=32, K=32) ----
        floatx4 acc2[2];
        acc2[0] = b2f[0];
        acc2[1] = b2f[1];
        const int c_a = mt2 * 16 + (lane & 15);
        #pragma unroll
        for (int k = 0; k < K_NUM; ++k) {
            int row = (k * TT + th) * 64 + c_a;
            int blk = ((lane >> 4) & 3) ^ ((c_a >> 2) & 3);
            short8 ha = *(const short8*)&((unsigned int*)H2)[row * 16 + blk * 4];
            #pragma unroll
            for (int nt = 0; nt < 2; ++nt)
                acc2[nt] = __builtin_amdgcn_mfma_f32_16x16x32_bf16(
                    ha, afr2[k][nt], acc2[nt], 0, 0, 0);
        }

        const int tg = t_base + ts * TT + th;
        const int c0 = mt2 * 16 + ((lane >> 4) & 3) * 4;
        const int wl = lane & 15;
        #pragma unroll
        for (int r = 0; r < 4; ++r)
            out[((size_t)(nb * C_OUT + c0 + r) * T_DIM + tg) * V_DIM + wl] = acc2[0][r];
        if (wl < 9) {
            #pragma unroll
            for (int r = 0; r < 4; ++r)
                out[((size_t)(nb * C_OUT + c0 + r) * T_DIM + tg) * V_DIM + 16 + wl] = acc2[1][r];
        }
    }
}

extern "C" void kernel_launch(void* const* d_in, const int* in_sizes, int n_in,
                              void* d_out, int out_size, void* d_ws, size_t ws_size,
                              hipStream_t stream) {
    const float* x = (const float*)d_in[0];
    const float* A = (const float*)d_in[1];
    const float* W = (const float*)d_in[2];
    const float* b = (const float*)d_in[3];
    float* out = (float*)d_out;

    unsigned short* wbuf = (unsigned short*)d_ws;
    unsigned short* abuf = (unsigned short*)((char*)d_ws + ABUF_OFF);
    float* b2buf = (float*)((char*)d_ws + B2_OFF);

    sgcn_prep<<<(WBUF_ELEMS + 255) / 256, 256, 0, stream>>>(W, A, b, wbuf, abuf, b2buf);

    dim3 grid(N_DIM * NWIN);   // 16 * 128 = 2048 blocks x 512 threads
    sgcn_main<<<grid, 512, 0, stream>>>(x, wbuf, abuf, b2buf, out);
}

// Round 16
// 120.975 us; speedup vs baseline: 1.0446x; 1.0446x over previous
//
#include <hip/hip_runtime.h>

// s_gcn, plain-bf16 MFMA, two fused GEMM stages.
// R13 base (single-barrier pipelined double-buffer, b128 staging writes).
// R16: VALU cut via pure-C round-half-up bf16 pair-pack (5 ops/pair vs ~10
//   for RNE). cvt_pk inline-asm is permanently abandoned: R11 regressed
//   (regalloc collapse) and R15 NaN'd (context-dependent asm/MFMA hazard).
//   Round-half-up differs from RNE only at ties (<=1 ulp); absmax budget ok.

typedef short short8 __attribute__((ext_vector_type(8)));
typedef float floatx4 __attribute__((ext_vector_type(4)));
typedef unsigned int uintx4 __attribute__((ext_vector_type(4)));

#define K_NUM 3
#define C_IN  64
#define C_OUT 64
#define T_DIM 2048
#define V_DIM 25
#define N_DIM 16

#define TT    2
#define NSUB  16
#define TWIN  32
#define XROW  51200   // T_DIM*V_DIM

#define WBUF_ELEMS (12*2*64*8)
#define ABUF_OFF   (WBUF_ELEMS*2)
#define ABUF_ELEMS (3*2*64*8)
#define B2_OFF     (ABUF_OFF + ABUF_ELEMS*2)
#define B2_ELEMS   (4*2*64*4)

__device__ __forceinline__ unsigned short bf16_rne(float f) {
    unsigned int u = __builtin_bit_cast(unsigned int, f);
    unsigned int r = (u + 0x7FFFu + ((u >> 16) & 1u)) >> 16;
    return (unsigned short)r;
}
// {bf16(fx) in lo16, bf16(fy) in hi16}, round-half-up (5 VALU ops)
__device__ __forceinline__ unsigned int pack_rh(float fx, float fy) {
    unsigned int ux = __builtin_bit_cast(unsigned int, fx);
    unsigned int uy = __builtin_bit_cast(unsigned int, fy);
    return ((ux + 0x8000u) >> 16) | ((uy + 0x8000u) & 0xFFFF0000u);
}

__global__ void sgcn_prep(const float* __restrict__ W, const float* __restrict__ A,
                          const float* __restrict__ b,
                          unsigned short* __restrict__ wbuf,
                          unsigned short* __restrict__ abuf,
                          float* __restrict__ b2buf) {
    int idx = blockIdx.x * 256 + threadIdx.x;
    if (idx < WBUF_ELEMS) {   // B-op: n=o, k=ci
        int j = idx & 7, lane = (idx >> 3) & 63, ks = (idx >> 9) & 1, nt = idx >> 10;
        int o  = nt * 16 + (lane & 15);
        int ci = ks * 32 + ((lane >> 4) & 3) * 8 + j;
        wbuf[idx] = bf16_rne(W[o * C_IN + ci]);
    }
    if (idx < ABUF_ELEMS) {   // B-op: n=w, k=v
        int j = idx & 7, lane = (idx >> 3) & 63, nt = (idx >> 9) & 1, k = idx >> 10;
        int w = nt * 16 + (lane & 15);
        int v = ((lane >> 4) & 3) * 8 + j;
        abuf[idx] = (v < V_DIM && w < V_DIM) ? bf16_rne(A[(k * V_DIM + v) * V_DIM + w])
                                             : (unsigned short)0;
    }
    if (idx < B2_ELEMS) {     // bias folded through stage-2
        int r = idx & 3, lane = (idx >> 2) & 63, nt = (idx >> 8) & 1, mt2 = idx >> 9;
        int c = mt2 * 16 + ((lane >> 4) & 3) * 4 + r;
        int w = nt * 16 + (lane & 15);
        float val = 0.f;
        if (w < V_DIM) {
            for (int k = 0; k < K_NUM; ++k) {
                float cs = 0.f;
                for (int v = 0; v < V_DIM; ++v) cs += A[(k * V_DIM + v) * V_DIM + w];
                val += b[k * C_OUT + c] * cs;
            }
        }
        b2buf[idx] = val;
    }
}

__global__ __launch_bounds__(512)
void sgcn_main(const float* __restrict__ x,
               const unsigned short* __restrict__ wbuf,
               const unsigned short* __restrict__ abuf,
               const float* __restrict__ b2buf,
               float* __restrict__ out) {
    __shared__ __align__(16) unsigned int   Xt[2][64 * 32];              // 2 x 8 KB
    __shared__ __align__(16) unsigned short H2[2][K_NUM * TT * 64 * 32]; // 2 x 24 KB

    const int tid  = threadIdx.x;
    const int lane = tid & 63;
    const int wid  = tid >> 6;
    const int nb   = blockIdx.x >> 6;
    const int t_base = (blockIdx.x & 63) * TWIN;

    const int wm2 = wid & 1;   // stage-1: col half (= t)
    const int wq  = wid >> 1;  // stage-1: o quarter
    const int mt2 = wid & 3, th = wid >> 2;   // stage-2: 4 c-tiles x 2 t

    // ---- hoisted loop-invariant fragments ----
    short8 wfr[3][2];
    #pragma unroll
    for (int ni = 0; ni < 3; ++ni)
        #pragma unroll
        for (int ks = 0; ks < 2; ++ks)
            wfr[ni][ks] = ((const short8*)wbuf)[(((wq * 3 + ni) * 2 + ks) * 64) + lane];
    short8 afr2[3][2];
    #pragma unroll
    for (int k = 0; k < 3; ++k)
        #pragma unroll
        for (int nt = 0; nt < 2; ++nt)
            afr2[k][nt] = ((const short8*)abuf)[((k * 2 + nt) * 64) + lane];
    floatx4 b2f[2];
    b2f[0] = reinterpret_cast<const floatx4*>(b2buf)[(mt2 * 2 + 0) * 64 + lane];
    b2f[1] = reinterpret_cast<const floatx4*>(b2buf)[(mt2 * 2 + 1) * 64 + lane];

    // zero never-written Xt pad cols (25..31, 57..63) in BOTH buffers
    for (int i = tid; i < 2 * 14 * 32; i += 512) {
        int bsel = i >= 14 * 32;
        int j = i - bsel * 14 * 32;
        int pc = j >> 5, ciw = j & 31;
        int col = (pc < 7) ? (25 + pc) : (50 + pc);
        Xt[bsel][col * 32 + ciw] = 0u;
    }

    // ---- x prefetch: one b128 item per thread (400 active) ----
    float xq[8];
    const float* xptr = x + ((size_t)nb * C_IN * T_DIM + t_base) * V_DIM;
    const int ciq = tid / 50, cg = tid % 50;       // item coords (tid<400)
    const int icol = (cg / 25) * 32 + (cg % 25);   // t*32 + v
    const int isw  = (ciq ^ ((icol >> 1) & 7)) * 4;

    auto LOADX = [&](int ts) {
        if (tid < 400) {
            const float* s = xptr + ts * (TT * V_DIM) + (size_t)(ciq * 8) * XROW + cg;
            #pragma unroll
            for (int r = 0; r < 8; ++r) xq[r] = s[(size_t)r * XROW];
        }
    };
    auto WRITEX = [&](int bsel) {
        if (tid < 400) {
            uintx4 pk;
            #pragma unroll
            for (int j = 0; j < 4; ++j)
                pk[j] = pack_rh(xq[2 * j], xq[2 * j + 1]);
            *reinterpret_cast<uintx4*>(&Xt[bsel][icol * 32 + isw]) = pk;
        }
    };

    LOADX(0);
    WRITEX(0);
    LOADX(1);

    #pragma unroll 1
    for (int ts = 0; ts <= NSUB; ++ts) {
        __syncthreads();   // the only barrier: fences Xt[cur] & H2[prv] producers
        const int cur = ts & 1, prv = 1 - cur;

        floatx4 acc1[2][3];
        short8 xfr[2][2];
        if (ts < NSUB) {
            // ---- stage-1 reads: H^T = Xt * W  (M=64 col, N=192 o, K=64) ----
            #pragma unroll
            for (int mi = 0; mi < 2; ++mi) {
                int acol = (wm2 * 2 + mi) * 16 + (lane & 15);
                #pragma unroll
                for (int ks = 0; ks < 2; ++ks) {
                    int blk = (ks * 4 + ((lane >> 4) & 3)) ^ ((acol >> 1) & 7);
                    xfr[mi][ks] = *(const short8*)&Xt[cur][acol * 32 + blk * 4];
                }
            }
        }

        // stage-2(ts-1) reads issued early (independent buffer)
        short8 ha[3];
        if (ts >= 1) {
            const int c_a = mt2 * 16 + (lane & 15);
            #pragma unroll
            for (int k = 0; k < K_NUM; ++k) {
                int row = (k * TT + th) * 64 + c_a;
                int blk = ((lane >> 4) & 3) ^ ((c_a >> 2) & 3);
                ha[k] = *(const short8*)&((const unsigned int*)H2[prv])[row * 16 + blk * 4];
            }
        }

        if (ts + 1 < NSUB) WRITEX(cur ^ 1);    // Xt[nxt]; disjoint from all reads
        if (ts + 2 < NSUB) LOADX(ts + 2);      // refill regs; hides under MFMA

        if (ts < NSUB) {
            #pragma unroll
            for (int mi = 0; mi < 2; ++mi)
                #pragma unroll
                for (int ni = 0; ni < 3; ++ni)
                    acc1[mi][ni] = floatx4{0.f, 0.f, 0.f, 0.f};
            #pragma unroll
            for (int mi = 0; mi < 2; ++mi)
                #pragma unroll
                for (int ni = 0; ni < 3; ++ni)
                    #pragma unroll
                    for (int ks = 0; ks < 2; ++ks)
                        acc1[mi][ni] = __builtin_amdgcn_mfma_f32_16x16x32_bf16(
                            xfr[mi][ks], wfr[ni][ks], acc1[mi][ni], 0, 0, 0);

            // H2[cur] write: 4 consecutive v per thread -> 2 pack_rh + 1 b64 write
            #pragma unroll
            for (int mi = 0; mi < 2; ++mi) {
                int vb = mi * 16 + ((lane >> 4) & 3) * 4;
                #pragma unroll
                for (int ni = 0; ni < 3; ++ni) {
                    int o = wq * 48 + ni * 16 + (lane & 15);
                    int k = o >> 6, c = o & 63;
                    int swv = vb ^ (((c >> 2) & 3) << 3);
                    unsigned long long lo = pack_rh(acc1[mi][ni][0], acc1[mi][ni][1]);
                    unsigned long long hi = pack_rh(acc1[mi][ni][2], acc1[mi][ni][3]);
                    int idx16 = ((k * TT + wm2) * 64 + c) * 32 + swv;
                    ((unsigned long long*)H2[cur])[idx16 >> 2] = lo | (hi << 32);
                }
            }
        }

        if (ts >= 1) {
            // ---- stage-2(ts-1): OUT[c][w] = sum_k H_k * A_k ----
            floatx4 acc2[2];
            acc2[0] = b2f[0];
            acc2[1] = b2f[1];
            #pragma unroll
            for (int k = 0; k < K_NUM; ++k)
                #pragma unroll
                for (int nt = 0; nt < 2; ++nt)
                    acc2[nt] = __builtin_amdgcn_mfma_f32_16x16x32_bf16(
                        ha[k], afr2[k][nt], acc2[nt], 0, 0, 0);

            const int tg = t_base + (ts - 1) * TT + th;
            const int c0 = mt2 * 16 + ((lane >> 4) & 3) * 4;
            const int wl = lane & 15;
            #pragma unroll
            for (int r = 0; r < 4; ++r)
                out[((size_t)(nb * C_OUT + c0 + r) * T_DIM + tg) * V_DIM + wl] = acc2[0][r];
            if (wl < 9) {
                #pragma unroll
                for (int r = 0; r < 4; ++r)
                    out[((size_t)(nb * C_OUT + c0 + r) * T_DIM + tg) * V_DIM + 16 + wl] = acc2[1][r];
            }
        }
    }
}

extern "C" void kernel_launch(void* const* d_in, const int* in_sizes, int n_in,
                              void* d_out, int out_size, void* d_ws, size_t ws_size,
                              hipStream_t stream) {
    const float* x = (const float*)d_in[0];
    const float* A = (const float*)d_in[1];
    const float* W = (const float*)d_in[2];
    const float* b = (const float*)d_in[3];
    float* out = (float*)d_out;

    unsigned short* wbuf = (unsigned short*)d_ws;
    unsigned short* abuf = (unsigned short*)((char*)d_ws + ABUF_OFF);
    float* b2buf = (float*)((char*)d_ws + B2_OFF);

    sgcn_prep<<<(WBUF_ELEMS + 255) / 256, 256, 0, stream>>>(W, A, b, wbuf, abuf, b2buf);

    dim3 grid(N_DIM * (T_DIM / TWIN));   // 1024 blocks x 512 threads
    sgcn_main<<<grid, 512, 0, stream>>>(x, wbuf, abuf, b2buf, out);
}